// Round 1
// baseline (4655.721 us; speedup 1.0000x reference)
//
#include <hip/hip_runtime.h>
#include <stdint.h>

// Keep mul+add sequences UNFUSED so we bit-match XLA:CPU's unfused MulAdd ops.
#pragma clang fp contract(off)

#define BE_C   256
#define N_C    4096
#define K_C    32
#define KP1_C  33
#define CH_C   64
#define NCH_C  64          // N_C / CH_C
#define NEG_C  (-1e30f)
#define HALF_N (524288u)   // N_C*BE_C/2 (legacy rng scheme)

// ---------------- XLA:CPU (Eigen3/Cephes transcription) exp ----------------
__device__ __forceinline__ float xla_exp(float x) {
  const float exp_hi = 88.3762626647950f;
  const float exp_lo = -88.3762626647949f;
  const float log2ef = 1.44269504088896341f;
  const float c1 = 0.693359375f;
  const float c2 = -2.12194440e-4f;
  const float p0 = 1.9875691500E-4f;
  const float p1 = 1.3981999507E-3f;
  const float p2 = 8.3334519073E-3f;
  const float p3 = 4.1665795894E-2f;
  const float p4 = 1.6666665459E-1f;
  const float p5 = 5.0000001201E-1f;
  float xc = fminf(fmaxf(x, exp_lo), exp_hi);
  float fx = floorf(xc * log2ef + 0.5f);
  float tmp = c1 * fx;
  float z = c2 * fx;
  float xx = xc - tmp;
  xx = xx - z;
  z = xx * xx;
  float y = xx * p0 + p1;
  y = y * xx + p2;
  y = y * xx + p3;
  y = y * xx + p4;
  y = y * xx + p5;
  y = y * z + xx;
  y = y + 1.0f;
  int ei = (int)fx;                       // fx in [-127,127], exact
  float s = __int_as_float((ei + 127) << 23);
  return fmaxf(y * s, x);
}

// ---------------- XLA:CPU (Eigen3/Cephes transcription) log ----------------
// Only called with x in [1, 2] here (1 + exp(-|d|) with exp(-|d|) >= 1e-4).
__device__ __forceinline__ float xla_log(float xin) {
  const float sqrthf = 0.707106781186547524f;
  const float p0 = 7.0376836292E-2f;
  const float p1 = -1.1514610310E-1f;
  const float p2 = 1.1676998740E-1f;
  const float p3 = -1.2420140846E-1f;
  const float p4 = 1.4249322787E-1f;
  const float p5 = -1.6668057665E-1f;
  const float p6 = 2.0000714765E-1f;
  const float p7 = -2.4999993993E-1f;
  const float p8 = 3.3333331174E-1f;
  const float q1 = -2.12194440e-4f;
  const float q2 = 0.693359375f;
  float x = fmaxf(xin, 1.17549435e-38f);
  unsigned ub = __float_as_uint(x);
  int emm0 = (int)(ub >> 23) - 0x7f;
  float e = 1.0f + (float)emm0;
  x = __uint_as_float((ub & 0x007fffffu) | 0x3f000000u);
  bool mlt = x < sqrthf;
  float tmp = mlt ? x : 0.0f;
  x = x - 1.0f;
  e = e - (mlt ? 1.0f : 0.0f);
  x = x + tmp;
  float x2 = x * x;
  float x3 = x2 * x;
  float y  = x * p0 + p1;
  float y1 = x * p3 + p4;
  float y2 = x * p6 + p7;
  y  = y * x + p2;
  y1 = y1 * x + p5;
  y2 = y2 * x + p8;
  y = y * x3 + y1;
  y = y * x3 + y2;
  y = y * x3;
  y1 = q1 * e;
  float t2 = 0.5f * x2;
  y = y + y1;
  x = x - t2;
  y2 = q2 * e;
  x = x + y;
  x = x + y2;
  return x;
}

// XLA elemental emitter log1p: |x|<1e-4 ? x*(1 - x/2) : log(x+1)
__device__ __forceinline__ float xla_log1p(float x) {
  float ax = fabsf(x);
  float fsmall = ((-0.5f * x) + 1.0f) * x;
  float flarge = xla_log(x + 1.0f);
  return (ax < 1e-4f) ? fsmall : flarge;
}

// jnp.logaddexp (no-NaN inputs here): max + log1p(exp(-|a-b|))
__device__ __forceinline__ float xla_logaddexp(float a, float b) {
  float mx = fmaxf(a, b);
  float d = a - b;
  float e = xla_exp(-fabsf(d));
  return mx + xla_log1p(e);
}

// Fast path for the marginals-only F scan (2e-2 tolerance).
__device__ __forceinline__ float fast_logaddexp(float a, float b) {
  float mx = fmaxf(a, b);
  float d = -fabsf(a - b);
  return mx + log1pf(__expf(d));
}

// ---------------- Threefry-2x32, key = (0, 42), 20 rounds ----------------
__device__ __forceinline__ unsigned rotl_(unsigned v, int r) {
  return (v << r) | (v >> (32 - r));
}

__device__ __forceinline__ void threefry_0_42(unsigned c0, unsigned c1,
                                              unsigned* o0, unsigned* o1) {
  const unsigned ks0 = 0u, ks1 = 42u, ks2 = 0x1BD11BDAu ^ 0u ^ 42u;
  unsigned x0 = c0 + ks0, x1 = c1 + ks1;
  x0 += x1; x1 = rotl_(x1, 13); x1 ^= x0;
  x0 += x1; x1 = rotl_(x1, 15); x1 ^= x0;
  x0 += x1; x1 = rotl_(x1, 26); x1 ^= x0;
  x0 += x1; x1 = rotl_(x1, 6);  x1 ^= x0;
  x0 += ks1; x1 += ks2 + 1u;
  x0 += x1; x1 = rotl_(x1, 17); x1 ^= x0;
  x0 += x1; x1 = rotl_(x1, 29); x1 ^= x0;
  x0 += x1; x1 = rotl_(x1, 16); x1 ^= x0;
  x0 += x1; x1 = rotl_(x1, 24); x1 ^= x0;
  x0 += ks2; x1 += ks0 + 2u;
  x0 += x1; x1 = rotl_(x1, 13); x1 ^= x0;
  x0 += x1; x1 = rotl_(x1, 15); x1 ^= x0;
  x0 += x1; x1 = rotl_(x1, 26); x1 ^= x0;
  x0 += x1; x1 = rotl_(x1, 6);  x1 ^= x0;
  x0 += ks0; x1 += ks1 + 3u;
  x0 += x1; x1 = rotl_(x1, 17); x1 ^= x0;
  x0 += x1; x1 = rotl_(x1, 29); x1 ^= x0;
  x0 += x1; x1 = rotl_(x1, 16); x1 ^= x0;
  x0 += x1; x1 = rotl_(x1, 24); x1 ^= x0;
  x0 += ks1; x1 += ks2 + 4u;
  x0 += x1; x1 = rotl_(x1, 13); x1 ^= x0;
  x0 += x1; x1 = rotl_(x1, 15); x1 ^= x0;
  x0 += x1; x1 = rotl_(x1, 26); x1 ^= x0;
  x0 += x1; x1 = rotl_(x1, 6);  x1 ^= x0;
  x0 += ks2; x1 += ks0 + 5u;
  *o0 = x0; *o1 = x1;
}

// RNG scheme toggle: 1 = jax_threefry_partitionable (default True in modern JAX),
//                    0 = legacy split-halves scheme. Flip if mask bits mismatch.
#define RNG_PARTITIONABLE 1

__device__ __forceinline__ float u01_from_idx(unsigned idx) {
  unsigned b0, b1, bits;
#if RNG_PARTITIONABLE
  threefry_0_42(0u, idx, &b0, &b1);     // counter = (hi=0, lo=idx)
  bits = b0 ^ b1;                        // 32-bit partitionable output
#else
  if (idx < HALF_N) { threefry_0_42(idx, idx + HALF_N, &b0, &b1); bits = b0; }
  else              { threefry_0_42(idx - HALF_N, idx, &b0, &b1); bits = b1; }
#endif
  unsigned fb = (bits >> 9) | 0x3f800000u;
  return __uint_as_float(fb) - 1.0f;
}

// ---------------- main kernel: one block per row b (b = bi*2 + ens) ----------------
__global__ __launch_bounds__(64, 1)
void EdgeSIMPLEBatched_39298950758997_kernel(const float* __restrict__ scores,
                                             float* __restrict__ out) {
  __shared__ float th_lds[N_C];                 // 16 KB: theta row
  __shared__ float u_lds[N_C];                  // 16 KB: uniforms for this row
  __shared__ float chk_lds[(NCH_C + 1) * KP1_C]; // 65x33: B checkpoints (every 64 rows)
  __shared__ float bch[(CH_C + 1) * KP1_C];     // 65x33: current regenerated B chunk

  const int b = blockIdx.x;
  const int t = threadIdx.x;
  const int j = t;                 // log-ESP state index held by this lane (0..32 active)
  const int bi = b >> 1;
  const int ens = b & 1;
  const float* srow = scores + bi * (N_C * 2) + ens;

  // Phase 0: stage theta row + uniforms. U layout: u[i,0,b] at flat i*BE + b.
  for (int i = t; i < N_C; i += 64) {
    th_lds[i] = srow[i * 2];
    u_lds[i] = u01_from_idx((unsigned)(i * BE_C + b));
  }
  __syncthreads();

  // Phase 1: backward scan B[i][j] = logaddexp(B[i+1][j], B[i+1][j-1] + th[i]),
  // B[N] = (0, NEG, ...). Checkpoint every 64 rows (rows 0,64,...,4096).
  float E = (j == 0) ? 0.0f : NEG_C;
  if (j <= K_C) chk_lds[NCH_C * KP1_C + j] = E;   // checkpoint for i = 4096
#pragma unroll 1
  for (int i = N_C - 1; i >= 0; --i) {
    float th = th_lds[i];
    float Em1 = __shfl_up(E, 1);
    float sh = ((j == 0) ? NEG_C : Em1) + th;
    E = xla_logaddexp(E, sh);
    if ((i & (CH_C - 1)) == 0 && j <= K_C) chk_lds[(i >> 6) * KP1_C + j] = E;
  }
  __syncthreads();

  const float logZ = chk_lds[K_C];  // B[0][k] = log e_k(all)  (marginals only)

  // Phase 2: forward pass, chunk by chunk.
  float F = (j == 0) ? 0.0f : NEG_C;  // F[0]
  int r = K_C;                        // sampling state (T = 1)
  const int jc = (j <= K_C) ? j : 0;  // clamped LDS index for idle lanes

#pragma unroll 1
  for (int c = 0; c < NCH_C; ++c) {
    // Regenerate B rows [64c .. 64c+64] into bch (bit-identical: restart from
    // exactly-stored f32 checkpoint and redo the same op sequence).
    float E2 = chk_lds[(c + 1) * KP1_C + jc];
    if (j <= K_C) bch[CH_C * KP1_C + j] = E2;
#pragma unroll 1
    for (int ii = CH_C - 1; ii >= 0; --ii) {
      float th = th_lds[c * CH_C + ii];
      float Em1 = __shfl_up(E2, 1);
      float sh = ((j == 0) ? NEG_C : Em1) + th;
      E2 = xla_logaddexp(E2, sh);
      if (j <= K_C) bch[ii * KP1_C + j] = E2;
    }
    __syncthreads();

#pragma unroll 1
    for (int ii = 0; ii < CH_C; ++ii) {
      const int i = c * CH_C + ii;
      const float th = th_lds[i];
      const float u = u_lds[i];

      // --- sampling (exact): candidate q_j for every possible r = j ---
      float Bi     = bch[ii * KP1_C + jc];                          // B[i][j]
      float Bip1m1 = bch[(ii + 1) * KP1_C + ((jc == 0) ? 0 : jc - 1)]; // B[i+1][max(j-1,0)]
      float logq = (th + Bip1m1) - Bi;
      float q = xla_exp(fminf(logq, 0.0f));
      float qsel = __shfl(q, r);                 // q at current r (uniform r)
      bool incl = (u < qsel) && (r > 0);

      // --- marginal (tolerant): log_ekm1 = logsumexp_j F[i][j] + B[i+1][k-1-j] ---
      float Brev = bch[(ii + 1) * KP1_C + (K_C - 1 - ((j < K_C) ? j : 0))];
      float comb = (j < K_C) ? (F + Brev) : -__builtin_inff();
      float amax = comb;
      for (int off = 32; off >= 1; off >>= 1) amax = fmaxf(amax, __shfl_xor(amax, off));
      float ex = (j < K_C) ? __expf(comb - amax) : 0.0f;
      float ssum = ex;
      for (int off = 32; off >= 1; off >>= 1) ssum += __shfl_xor(ssum, off);
      float logekm1 = __logf(ssum) + amax;
      float logp = (th + logekm1) - logZ;
      float m = __expf(logp);

      if (t == 0) {
        const int oidx = bi * (N_C * 2) + i * 2 + ens;
        const float s = incl ? 1.0f : 0.0f;
        out[oidx] = (s - m) + m;                 // straight-through value
        out[1048576 + oidx] = m;                 // marginals block
      }
      r -= incl ? 1 : 0;

      // --- F update (tolerant fast math) ---
      float Fm1 = __shfl_up(F, 1);
      float shf = ((j == 0) ? NEG_C : Fm1) + th;
      F = fast_logaddexp(F, shf);
    }
    __syncthreads();
  }
}

extern "C" void kernel_launch(void* const* d_in, const int* in_sizes, int n_in,
                              void* d_out, int out_size, void* d_ws, size_t ws_size,
                              hipStream_t stream) {
  (void)in_sizes; (void)n_in; (void)d_ws; (void)ws_size; (void)out_size;
  const float* scores = (const float*)d_in[0];
  float* out = (float*)d_out;
  EdgeSIMPLEBatched_39298950758997_kernel<<<dim3(BE_C), dim3(64), 0, stream>>>(scores, out);
}

// Round 2
// 3643.254 us; speedup vs baseline: 1.2779x; 1.2779x over previous
//
#include <hip/hip_runtime.h>
#include <stdint.h>

// Keep mul+add sequences UNFUSED so we bit-match XLA:CPU's unfused MulAdd ops.
#pragma clang fp contract(off)

#define BE_C   256
#define N_C    4096
#define K_C    32
#define KP1_C  33
#define CH_C   64
#define NCH_C  64          // N_C / CH_C
#define NEG_C  (-1e30f)

// ---------------- XLA:CPU (Eigen3/Cephes transcription) exp ----------------
__device__ __forceinline__ float xla_exp(float x) {
  const float exp_hi = 88.3762626647950f;
  const float exp_lo = -88.3762626647949f;
  const float log2ef = 1.44269504088896341f;
  const float c1 = 0.693359375f;
  const float c2 = -2.12194440e-4f;
  const float p0 = 1.9875691500E-4f;
  const float p1 = 1.3981999507E-3f;
  const float p2 = 8.3334519073E-3f;
  const float p3 = 4.1665795894E-2f;
  const float p4 = 1.6666665459E-1f;
  const float p5 = 5.0000001201E-1f;
  float xc = fminf(fmaxf(x, exp_lo), exp_hi);
  float fx = floorf(xc * log2ef + 0.5f);
  float tmp = c1 * fx;
  float z = c2 * fx;
  float xx = xc - tmp;
  xx = xx - z;
  z = xx * xx;
  float y = xx * p0 + p1;
  y = y * xx + p2;
  y = y * xx + p3;
  y = y * xx + p4;
  y = y * xx + p5;
  y = y * z + xx;
  y = y + 1.0f;
  int ei = (int)fx;                       // fx in [-127,127], exact
  float s = __int_as_float((ei + 127) << 23);
  return fmaxf(y * s, x);
}

// ---------------- XLA:CPU (Eigen3/Cephes transcription) log ----------------
__device__ __forceinline__ float xla_log(float xin) {
  const float sqrthf = 0.707106781186547524f;
  const float p0 = 7.0376836292E-2f;
  const float p1 = -1.1514610310E-1f;
  const float p2 = 1.1676998740E-1f;
  const float p3 = -1.2420140846E-1f;
  const float p4 = 1.4249322787E-1f;
  const float p5 = -1.6668057665E-1f;
  const float p6 = 2.0000714765E-1f;
  const float p7 = -2.4999993993E-1f;
  const float p8 = 3.3333331174E-1f;
  const float q1 = -2.12194440e-4f;
  const float q2 = 0.693359375f;
  float x = fmaxf(xin, 1.17549435e-38f);
  unsigned ub = __float_as_uint(x);
  int emm0 = (int)(ub >> 23) - 0x7f;
  float e = 1.0f + (float)emm0;
  x = __uint_as_float((ub & 0x007fffffu) | 0x3f000000u);
  bool mlt = x < sqrthf;
  float tmp = mlt ? x : 0.0f;
  x = x - 1.0f;
  e = e - (mlt ? 1.0f : 0.0f);
  x = x + tmp;
  float x2 = x * x;
  float x3 = x2 * x;
  float y  = x * p0 + p1;
  float y1 = x * p3 + p4;
  float y2 = x * p6 + p7;
  y  = y * x + p2;
  y1 = y1 * x + p5;
  y2 = y2 * x + p8;
  y = y * x3 + y1;
  y = y * x3 + y2;
  y = y * x3;
  y1 = q1 * e;
  float t2 = 0.5f * x2;
  y = y + y1;
  x = x - t2;
  y2 = q2 * e;
  x = x + y;
  x = x + y2;
  return x;
}

// XLA elemental emitter log1p: |x|<1e-4 ? x*(1 - x/2) : log(x+1)
__device__ __forceinline__ float xla_log1p(float x) {
  float ax = fabsf(x);
  float fsmall = ((-0.5f * x) + 1.0f) * x;
  float flarge = xla_log(x + 1.0f);
  return (ax < 1e-4f) ? fsmall : flarge;
}

// jnp.logaddexp (no-NaN inputs here): max + log1p(exp(-|a-b|))
__device__ __forceinline__ float xla_logaddexp(float a, float b) {
  float mx = fmaxf(a, b);
  float d = a - b;
  float e = xla_exp(-fabsf(d));
  return mx + xla_log1p(e);
}

// Fast path (2e-2 tolerance consumers only: marginals).
__device__ __forceinline__ float fast_logaddexp(float a, float b) {
  float mx = fmaxf(a, b);
  float d = -fabsf(a - b);
  return mx + log1pf(__expf(d));
}

// ---------------- Threefry-2x32, key = (0, 42), 20 rounds ----------------
__device__ __forceinline__ unsigned rotl_(unsigned v, int r) {
  return (v << r) | (v >> (32 - r));
}

__device__ __forceinline__ void threefry_0_42(unsigned c0, unsigned c1,
                                              unsigned* o0, unsigned* o1) {
  const unsigned ks0 = 0u, ks1 = 42u, ks2 = 0x1BD11BDAu ^ 0u ^ 42u;
  unsigned x0 = c0 + ks0, x1 = c1 + ks1;
  x0 += x1; x1 = rotl_(x1, 13); x1 ^= x0;
  x0 += x1; x1 = rotl_(x1, 15); x1 ^= x0;
  x0 += x1; x1 = rotl_(x1, 26); x1 ^= x0;
  x0 += x1; x1 = rotl_(x1, 6);  x1 ^= x0;
  x0 += ks1; x1 += ks2 + 1u;
  x0 += x1; x1 = rotl_(x1, 17); x1 ^= x0;
  x0 += x1; x1 = rotl_(x1, 29); x1 ^= x0;
  x0 += x1; x1 = rotl_(x1, 16); x1 ^= x0;
  x0 += x1; x1 = rotl_(x1, 24); x1 ^= x0;
  x0 += ks2; x1 += ks0 + 2u;
  x0 += x1; x1 = rotl_(x1, 13); x1 ^= x0;
  x0 += x1; x1 = rotl_(x1, 15); x1 ^= x0;
  x0 += x1; x1 = rotl_(x1, 26); x1 ^= x0;
  x0 += x1; x1 = rotl_(x1, 6);  x1 ^= x0;
  x0 += ks0; x1 += ks1 + 3u;
  x0 += x1; x1 = rotl_(x1, 17); x1 ^= x0;
  x0 += x1; x1 = rotl_(x1, 29); x1 ^= x0;
  x0 += x1; x1 = rotl_(x1, 16); x1 ^= x0;
  x0 += x1; x1 = rotl_(x1, 24); x1 ^= x0;
  x0 += ks1; x1 += ks2 + 4u;
  x0 += x1; x1 = rotl_(x1, 13); x1 ^= x0;
  x0 += x1; x1 = rotl_(x1, 15); x1 ^= x0;
  x0 += x1; x1 = rotl_(x1, 26); x1 ^= x0;
  x0 += x1; x1 = rotl_(x1, 6);  x1 ^= x0;
  x0 += ks2; x1 += ks0 + 5u;
  *o0 = x0; *o1 = x1;
}

__device__ __forceinline__ float u01_from_idx(unsigned idx) {
  unsigned b0, b1;
  threefry_0_42(0u, idx, &b0, &b1);     // jax_threefry_partitionable path
  unsigned bits = b0 ^ b1;
  unsigned fb = (bits >> 9) | 0x3f800000u;
  return __uint_as_float(fb) - 1.0f;
}

// ---------------- main kernel: one block (one wave) per row b = bi*2 + ens ----------------
__global__ __launch_bounds__(64, 1)
void EdgeSIMPLEBatched_39298950758997_kernel(const float* __restrict__ scores,
                                             float* __restrict__ out) {
  __shared__ float    th_lds[N_C];                  // 16 KB
  __shared__ unsigned mask_lds[N_C];                // 16 KB: per-i 32-bit incl mask (bits r-1)
  __shared__ float    chk_lds[(NCH_C + 1) * KP1_C]; // 65x33 exact-B checkpoints
  __shared__ union {
    float u[N_C];                                   // phase 0/1 only
    struct {
      float bch[(CH_C + 1) * KP1_C];                // 65x33 regenerated B chunk (fast)
      float fch[CH_C * KP1_C];                      // 64x(32 used, stride 33) F rows
    } p2;                                           // phase 2 only
  } ov;

  const int b = blockIdx.x;
  const int t = threadIdx.x;
  const int j = t;                 // log-ESP state index (0..32 active)
  const int bi = b >> 1;
  const int ens = b & 1;
  const float* srow = scores + bi * (N_C * 2) + ens;

  // Phase 0: stage theta + uniforms. U layout: u[i,0,b] at flat i*BE + b.
  for (int i = t; i < N_C; i += 64) {
    th_lds[i] = srow[i * 2];
    ov.u[i] = u01_from_idx((unsigned)(i * BE_C + b));
  }
  __syncthreads();

  // Phase 1: EXACT backward scan B[i][j] = logaddexp(B[i+1][j], B[i+1][j-1]+th[i]).
  // Fused: inclusion-probability mask per i (off the critical chain, ~free).
  float E = (j == 0) ? 0.0f : NEG_C;
  if (j <= K_C) chk_lds[NCH_C * KP1_C + j] = E;
#pragma unroll 1
  for (int i = N_C - 1; i >= 0; --i) {
    float th = th_lds[i];
    float u  = ov.u[i];
    float Em1 = __shfl_up(E, 1);
    float sh = ((j == 0) ? NEG_C : Em1) + th;
    float Enew = xla_logaddexp(E, sh);
    // mask bit for r=j: logq = (th + B[i+1][j-1]) - B[i][j]  (exact, same ops as ref)
    float logq = (th + Em1) - Enew;
    float q = xla_exp(fminf(logq, 0.0f));
    bool pred = (j >= 1) && (j <= K_C) && (u < q);
    unsigned long long bal = __ballot(pred);
    if (t == 0) mask_lds[i] = (unsigned)(bal >> 1);   // bits r=1..32 -> u32 bits 0..31
    E = Enew;
    if ((i & (CH_C - 1)) == 0 && j <= K_C) chk_lds[(i >> 6) * KP1_C + j] = E;
  }
  __syncthreads();

  const float logZ = chk_lds[K_C];    // exact B[0][k] (marginals only; 2e-2 tol)
  const int jc = (j <= K_C) ? j : 0;

  float F = (j == 0) ? 0.0f : NEG_C;  // F[0]
  int r = K_C;                        // sampling state (T = 1)

#pragma unroll 1
  for (int c = 0; c < NCH_C; ++c) {
    // --- fused fast regen (backward) + fast F scan (forward): 2 independent chains ---
    float E2 = chk_lds[(c + 1) * KP1_C + jc];
    if (j <= K_C) ov.p2.bch[CH_C * KP1_C + j] = E2;
#pragma unroll 1
    for (int ii = 0; ii < CH_C; ++ii) {
      const int ri = CH_C - 1 - ii;
      float thb = th_lds[c * CH_C + ri];
      float Em1b = __shfl_up(E2, 1);
      float shb = ((j == 0) ? NEG_C : Em1b) + thb;
      E2 = fast_logaddexp(E2, shb);
      if (j <= K_C) ov.p2.bch[ri * KP1_C + j] = E2;

      float thf = th_lds[c * CH_C + ii];
      if (j < K_C) ov.p2.fch[ii * KP1_C + j] = F;    // F[i] BEFORE update
      float Fm1 = __shfl_up(F, 1);
      float shf = ((j == 0) ? NEG_C : Fm1) + thf;
      F = fast_logaddexp(F, shf);
    }
    __syncthreads();

    // --- marginals, lane-parallel: lane t owns i = c*64 + t ---
    float comb[K_C];
    float amax = -__builtin_inff();
#pragma unroll
    for (int jj = 0; jj < K_C; ++jj) {
      float f = ov.p2.fch[t * KP1_C + jj];
      float bb = ov.p2.bch[(t + 1) * KP1_C + (K_C - 1 - jj)];
      comb[jj] = f + bb;
      amax = fmaxf(amax, comb[jj]);
    }
    float ssum = 0.0f;
#pragma unroll
    for (int jj = 0; jj < K_C; ++jj) ssum += __expf(comb[jj] - amax);
    float logekm1 = __logf(ssum) + amax;
    float thi = th_lds[c * CH_C + t];
    float m = __expf((thi + logekm1) - logZ);

    // --- sequential conditional-Poisson walk over this chunk (bit-exact bits) ---
    unsigned mymask = mask_lds[c * CH_C + t];
    unsigned incl_mine = 0u;
#pragma unroll
    for (int ii = 0; ii < CH_C; ++ii) {
      unsigned mm = __shfl(mymask, ii);
      unsigned bit = (mm >> ((r - 1) & 31)) & 1u;
      bit = (r > 0) ? bit : 0u;
      incl_mine = (t == ii) ? bit : incl_mine;
      r -= (int)bit;
    }

    // --- coalesced-ish outputs: lane t writes i = c*64 + t ---
    const int i = c * CH_C + t;
    const int oidx = bi * (N_C * 2) + i * 2 + ens;
    float sval = incl_mine ? ((1.0f - m) + m) : 0.0f;   // (s - m) + m, s in {0,1}
    out[oidx] = sval;
    out[1048576 + oidx] = m;
    __syncthreads();   // protect bch/fch before next chunk rewrites them
  }
}

extern "C" void kernel_launch(void* const* d_in, const int* in_sizes, int n_in,
                              void* d_out, int out_size, void* d_ws, size_t ws_size,
                              hipStream_t stream) {
  (void)in_sizes; (void)n_in; (void)d_ws; (void)ws_size; (void)out_size;
  const float* scores = (const float*)d_in[0];
  float* out = (float*)d_out;
  EdgeSIMPLEBatched_39298950758997_kernel<<<dim3(BE_C), dim3(64), 0, stream>>>(scores, out);
}

// Round 3
// 1697.721 us; speedup vs baseline: 2.7423x; 2.1460x over previous
//
#include <hip/hip_runtime.h>
#include <stdint.h>

// Keep mul+add sequences UNFUSED so we bit-match XLA:CPU's unfused MulAdd ops.
#pragma clang fp contract(off)

#define BE_C     256
#define N_C      4096
#define K_C      32
#define NEG_C    (-1e30f)
#define OUT_HALF 1048576

// ---------------- XLA:CPU (Eigen3/Cephes transcription) exp ----------------
__device__ __forceinline__ float xla_exp(float x) {
  const float exp_hi = 88.3762626647950f;
  const float exp_lo = -88.3762626647949f;
  const float log2ef = 1.44269504088896341f;
  const float c1 = 0.693359375f;
  const float c2 = -2.12194440e-4f;
  const float p0 = 1.9875691500E-4f;
  const float p1 = 1.3981999507E-3f;
  const float p2 = 8.3334519073E-3f;
  const float p3 = 4.1665795894E-2f;
  const float p4 = 1.6666665459E-1f;
  const float p5 = 5.0000001201E-1f;
  float xc = fminf(fmaxf(x, exp_lo), exp_hi);
  float fx = floorf(xc * log2ef + 0.5f);
  float tmp = c1 * fx;
  float z = c2 * fx;
  float xx = xc - tmp;
  xx = xx - z;
  z = xx * xx;
  float y = xx * p0 + p1;
  y = y * xx + p2;
  y = y * xx + p3;
  y = y * xx + p4;
  y = y * xx + p5;
  y = y * z + xx;
  y = y + 1.0f;
  int ei = (int)fx;                       // fx in [-128,128], exact
  float s = __int_as_float((ei + 127) << 23);
  return fmaxf(y * s, x);
}

// ---------------- XLA:CPU (Eigen3/Cephes transcription) log ----------------
__device__ __forceinline__ float xla_log(float xin) {
  const float sqrthf = 0.707106781186547524f;
  const float p0 = 7.0376836292E-2f;
  const float p1 = -1.1514610310E-1f;
  const float p2 = 1.1676998740E-1f;
  const float p3 = -1.2420140846E-1f;
  const float p4 = 1.4249322787E-1f;
  const float p5 = -1.6668057665E-1f;
  const float p6 = 2.0000714765E-1f;
  const float p7 = -2.4999993993E-1f;
  const float p8 = 3.3333331174E-1f;
  const float q1 = -2.12194440e-4f;
  const float q2 = 0.693359375f;
  float x = fmaxf(xin, 1.17549435e-38f);
  unsigned ub = __float_as_uint(x);
  int emm0 = (int)(ub >> 23) - 0x7f;
  float e = 1.0f + (float)emm0;
  x = __uint_as_float((ub & 0x007fffffu) | 0x3f000000u);
  bool mlt = x < sqrthf;
  float tmp = mlt ? x : 0.0f;
  x = x - 1.0f;
  e = e - (mlt ? 1.0f : 0.0f);
  x = x + tmp;
  float x2 = x * x;
  float x3 = x2 * x;
  float y  = x * p0 + p1;
  float y1 = x * p3 + p4;
  float y2 = x * p6 + p7;
  y  = y * x + p2;
  y1 = y1 * x + p5;
  y2 = y2 * x + p8;
  y = y * x3 + y1;
  y = y * x3 + y2;
  y = y * x3;
  y1 = q1 * e;
  float t2 = 0.5f * x2;
  y = y + y1;
  x = x - t2;
  y2 = q2 * e;
  x = x + y;
  x = x + y2;
  return x;
}

// XLA elemental emitter log1p: |x|<1e-4 ? x*(1 - x/2) : log(x+1)
__device__ __forceinline__ float xla_log1p(float x) {
  float ax = fabsf(x);
  float fsmall = ((-0.5f * x) + 1.0f) * x;
  float flarge = xla_log(x + 1.0f);
  return (ax < 1e-4f) ? fsmall : flarge;
}

// jnp.logaddexp (no-NaN inputs here): max + log1p(exp(-|a-b|))
__device__ __forceinline__ float xla_logaddexp(float a, float b) {
  float mx = fmaxf(a, b);
  float d = a - b;
  float e = xla_exp(-fabsf(d));
  return mx + xla_log1p(e);
}

// Fast path (2e-2 tolerance consumers only): __logf instead of libm log1pf.
__device__ __forceinline__ float fast_la(float a, float b) {
  float mx = fmaxf(a, b);
  float d = a - b;
  float e = __expf(-fabsf(d));
  return mx + __logf(1.0f + e);
}

// Full-wave shift-right-by-1 via DPP (wave_shr:1 = 0x138, gfx9/CDNA).
// Lane 0 receives `fill`; lane l>0 receives lane l-1's value. Pure VALU.
__device__ __forceinline__ float dpp_shr1(float x, float fill) {
  int r = __builtin_amdgcn_update_dpp(__float_as_int(fill), __float_as_int(x),
                                      0x138, 0xF, 0xF, false);
  return __int_as_float(r);
}

// ---------------- Threefry-2x32, key = (0, 42), 20 rounds ----------------
__device__ __forceinline__ unsigned rotl_(unsigned v, int r) {
  return (v << r) | (v >> (32 - r));
}

__device__ __forceinline__ void threefry_0_42(unsigned c0, unsigned c1,
                                              unsigned* o0, unsigned* o1) {
  const unsigned ks0 = 0u, ks1 = 42u, ks2 = 0x1BD11BDAu ^ 0u ^ 42u;
  unsigned x0 = c0 + ks0, x1 = c1 + ks1;
  x0 += x1; x1 = rotl_(x1, 13); x1 ^= x0;
  x0 += x1; x1 = rotl_(x1, 15); x1 ^= x0;
  x0 += x1; x1 = rotl_(x1, 26); x1 ^= x0;
  x0 += x1; x1 = rotl_(x1, 6);  x1 ^= x0;
  x0 += ks1; x1 += ks2 + 1u;
  x0 += x1; x1 = rotl_(x1, 17); x1 ^= x0;
  x0 += x1; x1 = rotl_(x1, 29); x1 ^= x0;
  x0 += x1; x1 = rotl_(x1, 16); x1 ^= x0;
  x0 += x1; x1 = rotl_(x1, 24); x1 ^= x0;
  x0 += ks2; x1 += ks0 + 2u;
  x0 += x1; x1 = rotl_(x1, 13); x1 ^= x0;
  x0 += x1; x1 = rotl_(x1, 15); x1 ^= x0;
  x0 += x1; x1 = rotl_(x1, 26); x1 ^= x0;
  x0 += x1; x1 = rotl_(x1, 6);  x1 ^= x0;
  x0 += ks0; x1 += ks1 + 3u;
  x0 += x1; x1 = rotl_(x1, 17); x1 ^= x0;
  x0 += x1; x1 = rotl_(x1, 29); x1 ^= x0;
  x0 += x1; x1 = rotl_(x1, 16); x1 ^= x0;
  x0 += x1; x1 = rotl_(x1, 24); x1 ^= x0;
  x0 += ks1; x1 += ks2 + 4u;
  x0 += x1; x1 = rotl_(x1, 13); x1 ^= x0;
  x0 += x1; x1 = rotl_(x1, 15); x1 ^= x0;
  x0 += x1; x1 = rotl_(x1, 26); x1 ^= x0;
  x0 += x1; x1 = rotl_(x1, 6);  x1 ^= x0;
  x0 += ks2; x1 += ks0 + 5u;
  *o0 = x0; *o1 = x1;
}

__device__ __forceinline__ float u01_from_idx(unsigned idx) {
  unsigned b0, b1;
  threefry_0_42(0u, idx, &b0, &b1);     // jax_threefry_partitionable path
  unsigned bits = b0 ^ b1;
  unsigned fb = (bits >> 9) | 0x3f800000u;
  return __uint_as_float(fb) - 1.0f;
}

// ---------------- main kernel: one block (4 waves) per row b = bi*2 + ens ----------------
__global__ __launch_bounds__(256)
void EdgeSIMPLEBatched_39298950758997_kernel(const float* __restrict__ scores,
                                             float* __restrict__ out) {
  __shared__ float th_lds[N_C];          // 16 KB
  __shared__ float chkB[64 * 32];        // chkB[c] = exact B-row 64(c+1), cols 0..31
  __shared__ float chkF[63 * 32];        // chkF[c-1] = fast F-state at chunk-c start
  __shared__ float logZ_s;
  __shared__ union OvT {
    float u[N_C];                        // phase 0/1: uniforms
    float bch[4][64 * 32];               // phase 2: per-wave B chunk (rows = B[i+1])
  } ov;

  const int t = threadIdx.x;
  const int w = t >> 6;
  const int lane = t & 63;
  const int b = blockIdx.x;
  const int bi = b >> 1, ens = b & 1;
  const float* srow = scores + bi * (N_C * 2) + ens;

  // ---- Phase 0: stage theta + uniforms (all 4 waves) ----
  for (int idx = t; idx < N_C; idx += 256) {
    th_lds[idx] = srow[idx * 2];
    ov.u[idx] = u01_from_idx((unsigned)(idx * BE_C + b));
  }
  __syncthreads();

  // ---- Phase 1 ----
  if (w == 0) {
    // EXACT backward B scan + inclusion-mask ballot (op-for-op = round 2).
    float E = (lane == 0) ? 0.0f : NEG_C;
    if (lane < 32) chkB[63 * 32 + lane] = E;     // B-row 4096 = init
    float th = th_lds[N_C - 1];
    float u  = ov.u[N_C - 1];
#pragma unroll 2
    for (int i = N_C - 1; i >= 0; --i) {
      const int ip = (i > 0) ? i - 1 : 0;
      float th_nx = th_lds[ip];                  // prefetch next iter (off-chain)
      float u_nx  = ov.u[ip];
      float Em1 = dpp_shr1(E, NEG_C);            // B[i+1][j-1], lane0 = NEG
      float sh = Em1 + th;
      float Enew = xla_logaddexp(E, sh);         // exact chain
      float logq = (th + Em1) - Enew;            // exact, ref op order
      float q = xla_exp(fminf(logq, 0.0f));
      unsigned long long bal = __ballot(u < q);
      unsigned msk = (unsigned)(bal >> 1);       // bits 0..31 <- lanes j=1..32 (r=j)
      if (lane == 0) out[bi * (N_C * 2) + i * 2 + ens] = __uint_as_float(msk); // stash
      E = Enew;
      if ((i & 63) == 0 && i > 0 && lane < 32) chkB[((i >> 6) - 1) * 32 + lane] = E;
      th = th_nx; u = u_nx;
    }
    if (lane == 32) logZ_s = E;                  // B[0][k]
  } else if (w == 1) {
    // Fast forward F scan, checkpoint every 64 (runs concurrently with wave 0).
    float F = (lane == 0) ? 0.0f : NEG_C;
    float th = th_lds[0];
#pragma unroll 2
    for (int i = 0; i < N_C; ++i) {
      float th_nx = th_lds[(i + 1 < N_C) ? i + 1 : i];
      if ((i & 63) == 0 && i > 0 && lane < 32) chkF[((i >> 6) - 1) * 32 + lane] = F;
      float Fm1 = dpp_shr1(F, NEG_C);
      F = fast_la(F, Fm1 + th);
      th = th_nx;
    }
  }
  __syncthreads();

  // ---- Phase 2: marginals, 4-wave chunk-parallel ----
  const float logZ = logZ_s;
  float* bch = ov.bch[w];
  for (int c = w; c < 64; c += 4) {
    // Regenerate B rows c*64+1 .. c*64+64 (= B[i+1] for ii=0..63) into bch.
    float E2 = chkB[c * 32 + (lane & 31)];       // B-row 64(c+1)
    if (lane < 32) bch[63 * 32 + lane] = E2;
#pragma unroll 1
    for (int ii = 63; ii >= 1; --ii) {
      float th = th_lds[c * 64 + ii];
      float Em1 = dpp_shr1(E2, NEG_C);
      E2 = fast_la(E2, Em1 + th);                // B-row c*64+ii
      if (lane < 32) bch[(ii - 1) * 32 + lane] = E2;
    }
    // F forward over the chunk, fused marginal (butterfly logsumexp over 32 lanes).
    float F2;
    if (c == 0) F2 = (lane == 0) ? 0.0f : NEG_C;
    else        F2 = (lane < 32) ? chkF[(c - 1) * 32 + lane] : NEG_C;
    float m_mine = 0.0f;
#pragma unroll 2
    for (int ii = 0; ii < 64; ++ii) {
      float th = th_lds[c * 64 + ii];
      float bb = bch[ii * 32 + ((31 - lane) & 31)];              // B[i+1][31-j]
      float comb = (lane < 32) ? (F2 + bb) : -__builtin_inff();  // F[i][j] + ...
      float amax = comb;
      amax = fmaxf(amax, __shfl_xor(amax, 1));
      amax = fmaxf(amax, __shfl_xor(amax, 2));
      amax = fmaxf(amax, __shfl_xor(amax, 4));
      amax = fmaxf(amax, __shfl_xor(amax, 8));
      amax = fmaxf(amax, __shfl_xor(amax, 16));
      amax = fmaxf(amax, __shfl_xor(amax, 32));
      float ex = __expf(comb - amax);                            // lanes>=32 -> 0
      float ss = ex;
      ss += __shfl_xor(ss, 1);
      ss += __shfl_xor(ss, 2);
      ss += __shfl_xor(ss, 4);
      ss += __shfl_xor(ss, 8);
      ss += __shfl_xor(ss, 16);
      ss += __shfl_xor(ss, 32);
      float m = __expf((th + (__logf(ss) + amax)) - logZ);
      m_mine = (lane == ii) ? m : m_mine;
      float Fm1 = dpp_shr1(F2, NEG_C);
      F2 = fast_la(F2, Fm1 + th);
    }
    const int i = c * 64 + lane;
    out[OUT_HALF + bi * (N_C * 2) + i * 2 + ens] = m_mine;       // coalesced-ish
  }
  __syncthreads();

  // ---- Phase 3: sequential conditional-Poisson walk (wave 0), bit-exact ----
  if (w == 0) {
    int r = K_C;
    for (int c = 0; c < 64; ++c) {
      const int i = c * 64 + lane;
      const int oidx = bi * (N_C * 2) + i * 2 + ens;
      float mval = out[OUT_HALF + oidx];
      unsigned mymask = __float_as_uint(out[oidx]);              // stashed mask
      unsigned incl = 0u;
#pragma unroll 8
      for (int ii = 0; ii < 64; ++ii) {
        unsigned mm = (unsigned)__builtin_amdgcn_readlane((int)mymask, ii);
        unsigned bit = (mm >> ((unsigned)(r - 1) & 31u)) & 1u;
        bit = (r > 0) ? bit : 0u;
        if (lane == ii) incl = bit;
        r -= (int)bit;
      }
      float sval = incl ? ((1.0f - mval) + mval) : 0.0f;         // (s-m)+m
      out[oidx] = sval;
    }
  }
}

extern "C" void kernel_launch(void* const* d_in, const int* in_sizes, int n_in,
                              void* d_out, int out_size, void* d_ws, size_t ws_size,
                              hipStream_t stream) {
  (void)in_sizes; (void)n_in; (void)d_ws; (void)ws_size; (void)out_size;
  const float* scores = (const float*)d_in[0];
  float* out = (float*)d_out;
  EdgeSIMPLEBatched_39298950758997_kernel<<<dim3(BE_C), dim3(256), 0, stream>>>(scores, out);
}

// Round 4
// 1234.591 us; speedup vs baseline: 3.7711x; 1.3751x over previous
//
#include <hip/hip_runtime.h>
#include <stdint.h>

// Keep mul+add sequences UNFUSED so we bit-match XLA:CPU's unfused MulAdd ops.
#pragma clang fp contract(off)

#define BE_C     256
#define N_C      4096
#define K_C      32
#define NEG_C    (-1e30f)
#define OUT_HALF 1048576

// ---------------- XLA:CPU (Eigen3/Cephes transcription) exp ----------------
__device__ __forceinline__ float xla_exp(float x) {
  const float exp_hi = 88.3762626647950f;
  const float exp_lo = -88.3762626647949f;
  const float log2ef = 1.44269504088896341f;
  const float c1 = 0.693359375f;
  const float c2 = -2.12194440e-4f;
  const float p0 = 1.9875691500E-4f;
  const float p1 = 1.3981999507E-3f;
  const float p2 = 8.3334519073E-3f;
  const float p3 = 4.1665795894E-2f;
  const float p4 = 1.6666665459E-1f;
  const float p5 = 5.0000001201E-1f;
  float xc = fminf(fmaxf(x, exp_lo), exp_hi);
  float fx = floorf(xc * log2ef + 0.5f);
  float tmp = c1 * fx;
  float z = c2 * fx;
  float xx = xc - tmp;
  xx = xx - z;
  z = xx * xx;
  float y = xx * p0 + p1;
  y = y * xx + p2;
  y = y * xx + p3;
  y = y * xx + p4;
  y = y * xx + p5;
  y = y * z + xx;
  y = y + 1.0f;
  int ei = (int)fx;                       // fx in [-128,128], exact
  float s = __int_as_float((ei + 127) << 23);
  return fmaxf(y * s, x);
}

// ---------------- XLA:CPU (Eigen3/Cephes transcription) log ----------------
__device__ __forceinline__ float xla_log(float xin) {
  const float sqrthf = 0.707106781186547524f;
  const float p0 = 7.0376836292E-2f;
  const float p1 = -1.1514610310E-1f;
  const float p2 = 1.1676998740E-1f;
  const float p3 = -1.2420140846E-1f;
  const float p4 = 1.4249322787E-1f;
  const float p5 = -1.6668057665E-1f;
  const float p6 = 2.0000714765E-1f;
  const float p7 = -2.4999993993E-1f;
  const float p8 = 3.3333331174E-1f;
  const float q1 = -2.12194440e-4f;
  const float q2 = 0.693359375f;
  float x = fmaxf(xin, 1.17549435e-38f);
  unsigned ub = __float_as_uint(x);
  int emm0 = (int)(ub >> 23) - 0x7f;
  float e = 1.0f + (float)emm0;
  x = __uint_as_float((ub & 0x007fffffu) | 0x3f000000u);
  bool mlt = x < sqrthf;
  float tmp = mlt ? x : 0.0f;
  x = x - 1.0f;
  e = e - (mlt ? 1.0f : 0.0f);
  x = x + tmp;
  float x2 = x * x;
  float x3 = x2 * x;
  float y  = x * p0 + p1;
  float y1 = x * p3 + p4;
  float y2 = x * p6 + p7;
  y  = y * x + p2;
  y1 = y1 * x + p5;
  y2 = y2 * x + p8;
  y = y * x3 + y1;
  y = y * x3 + y2;
  y = y * x3;
  y1 = q1 * e;
  float t2 = 0.5f * x2;
  y = y + y1;
  x = x - t2;
  y2 = q2 * e;
  x = x + y;
  x = x + y2;
  return x;
}

// XLA elemental emitter log1p: |x|<1e-4 ? x*(1 - x/2) : log(x+1)
__device__ __forceinline__ float xla_log1p(float x) {
  float ax = fabsf(x);
  float fsmall = ((-0.5f * x) + 1.0f) * x;
  float flarge = xla_log(x + 1.0f);
  return (ax < 1e-4f) ? fsmall : flarge;
}

// jnp.logaddexp (no-NaN inputs here): max + log1p(exp(-|a-b|))
__device__ __forceinline__ float xla_logaddexp(float a, float b) {
  float mx = fmaxf(a, b);
  float d = a - b;
  float e = xla_exp(-fabsf(d));
  return mx + xla_log1p(e);
}

// Fast path (2e-2 tolerance consumers only: marginals).
__device__ __forceinline__ float fast_la(float a, float b) {
  float mx = fmaxf(a, b);
  float d = a - b;
  float e = __expf(-fabsf(d));
  return mx + __logf(1.0f + e);
}

// Full-wave shift-right-by-1 via DPP (wave_shr:1 = 0x138). Lane 0 <- fill.
__device__ __forceinline__ float dpp_shr1(float x, float fill) {
  int r = __builtin_amdgcn_update_dpp(__float_as_int(fill), __float_as_int(x),
                                      0x138, 0xF, 0xF, false);
  return __int_as_float(r);
}

// ---------------- Threefry-2x32, key = (0, 42), 20 rounds ----------------
__device__ __forceinline__ unsigned rotl_(unsigned v, int r) {
  return (v << r) | (v >> (32 - r));
}

__device__ __forceinline__ void threefry_0_42(unsigned c0, unsigned c1,
                                              unsigned* o0, unsigned* o1) {
  const unsigned ks0 = 0u, ks1 = 42u, ks2 = 0x1BD11BDAu ^ 0u ^ 42u;
  unsigned x0 = c0 + ks0, x1 = c1 + ks1;
  x0 += x1; x1 = rotl_(x1, 13); x1 ^= x0;
  x0 += x1; x1 = rotl_(x1, 15); x1 ^= x0;
  x0 += x1; x1 = rotl_(x1, 26); x1 ^= x0;
  x0 += x1; x1 = rotl_(x1, 6);  x1 ^= x0;
  x0 += ks1; x1 += ks2 + 1u;
  x0 += x1; x1 = rotl_(x1, 17); x1 ^= x0;
  x0 += x1; x1 = rotl_(x1, 29); x1 ^= x0;
  x0 += x1; x1 = rotl_(x1, 16); x1 ^= x0;
  x0 += x1; x1 = rotl_(x1, 24); x1 ^= x0;
  x0 += ks2; x1 += ks0 + 2u;
  x0 += x1; x1 = rotl_(x1, 13); x1 ^= x0;
  x0 += x1; x1 = rotl_(x1, 15); x1 ^= x0;
  x0 += x1; x1 = rotl_(x1, 26); x1 ^= x0;
  x0 += x1; x1 = rotl_(x1, 6);  x1 ^= x0;
  x0 += ks0; x1 += ks1 + 3u;
  x0 += x1; x1 = rotl_(x1, 17); x1 ^= x0;
  x0 += x1; x1 = rotl_(x1, 29); x1 ^= x0;
  x0 += x1; x1 = rotl_(x1, 16); x1 ^= x0;
  x0 += x1; x1 = rotl_(x1, 24); x1 ^= x0;
  x0 += ks1; x1 += ks2 + 4u;
  x0 += x1; x1 = rotl_(x1, 13); x1 ^= x0;
  x0 += x1; x1 = rotl_(x1, 15); x1 ^= x0;
  x0 += x1; x1 = rotl_(x1, 26); x1 ^= x0;
  x0 += x1; x1 = rotl_(x1, 6);  x1 ^= x0;
  x0 += ks2; x1 += ks0 + 5u;
  *o0 = x0; *o1 = x1;
}

__device__ __forceinline__ float u01_from_idx(unsigned idx) {
  unsigned b0, b1;
  threefry_0_42(0u, idx, &b0, &b1);     // jax_threefry_partitionable
  unsigned bits = b0 ^ b1;
  unsigned fb = (bits >> 9) | 0x3f800000u;
  return __uint_as_float(fb) - 1.0f;
}

// XOR-swizzled 64x32 tile: conflict-free col-writes AND row-reads.
__device__ __forceinline__ int sw_idx(int row, int col) {
  return row * 32 + ((col + row) & 31);
}

// ---------------- main kernel: one block (4 waves) per row b = bi*2 + ens ----------------
__global__ __launch_bounds__(256)
void EdgeSIMPLEBatched_39298950758997_kernel(const float* __restrict__ scores,
                                             float* __restrict__ out) {
  __shared__ float th_lds[N_C];          // 16384 B
  __shared__ float chkB[64 * 32];        // 8192 B: chkB[c] = exact B-row 64(c+1)
  __shared__ float chkF[63 * 32];        // 8064 B: chkF[c-1] = F-state at chunk c
  __shared__ float logZ_s;
  __shared__ int   prodCnt;              // batches produced (producer wave 0)
  __shared__ int   consCnt[2];           // [0]=wave2 (even b), [1]=wave3 (odd b)
  __shared__ union OvT {
    struct {
      float u[N_C];                      // 16384 B: uniforms (phase 0/1)
      float ring[2 * 32 * 64];           // 16384 B: 2 slots x 32 rows x 64 lanes
    } p1;
    float wbuf[4][64 * 32];              // 32768 B: per-wave B/comb tile (phase 2)
  } ov;

  const int t = threadIdx.x;
  const int w = t >> 6;
  const int lane = t & 63;
  const int b = blockIdx.x;
  const int bi = b >> 1, ens = b & 1;
  const float* srow = scores + bi * (N_C * 2) + ens;

  // ---- Phase 0: stage theta + uniforms; zero flags ----
  for (int idx = t; idx < N_C; idx += 256) {
    th_lds[idx] = srow[idx * 2];
    ov.p1.u[idx] = u01_from_idx((unsigned)(idx * BE_C + b));
  }
  if (t == 0) { prodCnt = 0; consCnt[0] = 0; consCnt[1] = 0; }
  __syncthreads();

  // ---- Phase 1: producer/consumer split ----
  if (w == 0) {
    // PRODUCER: pure exact B chain; hand logq rows to consumers via LDS ring.
    float E = (lane == 0) ? 0.0f : NEG_C;
    if (lane < 32) chkB[63 * 32 + lane] = E;     // B-row 4096 = init
    float th = th_lds[N_C - 1];
#pragma unroll 1
    for (int bb = 0; bb < 128; ++bb) {
      if (bb >= 2) {      // back-pressure: slot (bb&1) free when batch bb-2 consumed
        volatile int* cc = &consCnt[bb & 1];
        while (*cc < bb - 1) __builtin_amdgcn_s_sleep(1);
      }
      float* ring = ov.p1.ring + (bb & 1) * (32 * 64);
#pragma unroll 2
      for (int l = 0; l < 32; ++l) {
        const int i = N_C - 1 - (bb * 32 + l);
        const int ip = (i > 0) ? i - 1 : 0;
        float th_nx = th_lds[ip];                // off-chain prefetch
        float Em1 = dpp_shr1(E, NEG_C);          // B[i+1][j-1]
        float sh = Em1 + th;
        float Enew = xla_logaddexp(E, sh);       // EXACT chain
        float logq = (th + Em1) - Enew;          // exact, ref op order
        ring[l * 64 + lane] = logq;
        E = Enew;
        if ((i & 63) == 0 && i > 0 && lane < 32) chkB[((i >> 6) - 1) * 32 + lane] = E;
        th = th_nx;
      }
      __threadfence_block();                     // drain ds writes before flag
      if (lane == 0) *(volatile int*)&prodCnt = bb + 1;
    }
    if (lane == 32) logZ_s = E;                  // B[0][k]
  } else if (w == 1) {
    // Fast forward F scan, checkpoint every 64 rows.
    float F = (lane == 0) ? 0.0f : NEG_C;
    float th = th_lds[0];
#pragma unroll 2
    for (int i = 0; i < N_C; ++i) {
      float th_nx = th_lds[(i + 1 < N_C) ? i + 1 : i];
      if ((i & 63) == 0 && i > 0 && lane < 32) chkF[((i >> 6) - 1) * 32 + lane] = F;
      float Fm1 = dpp_shr1(F, NEG_C);
      F = fast_la(F, Fm1 + th);
      th = th_nx;
    }
  } else {
    // CONSUMERS (w=2 even batches, w=3 odd): mask bits from logq rows.
    const int par = w - 2;
#pragma unroll 1
    for (int bb = par; bb < 128; bb += 2) {
      { volatile int* pc = &prodCnt;
        while (*pc < bb + 1) __builtin_amdgcn_s_sleep(1); }
      float* ring = ov.p1.ring + (bb & 1) * (32 * 64);
#pragma unroll 2
      for (int l = 0; l < 32; ++l) {
        const int i = N_C - 1 - (bb * 32 + l);
        float logq = ring[l * 64 + lane];
        float u = ov.p1.u[i];
        float q = xla_exp(fminf(logq, 0.0f));    // exact, ref op order
        unsigned long long bal = __ballot(u < q);
        if (lane == 0)
          out[bi * (N_C * 2) + i * 2 + ens] = __uint_as_float((unsigned)(bal >> 1));
      }
      __threadfence_block();                     // ring reads done before freeing slot
      if (lane == 0) *(volatile int*)&consCnt[par] = bb + 1;
    }
  }
  __syncthreads();

  // ---- Phase 2: marginals, 4-wave chunk-parallel, per-lane register logsumexp ----
  const float logZ = logZ_s;
  float* wb = ov.wbuf[w];
  for (int c = w; c < 64; c += 4) {
    // Regen B rows c*64+1 .. c*64+64 into wb (row ii holds B[c*64+ii+1]).
    float E2 = chkB[c * 32 + (lane & 31)];
    if (lane < 32) wb[sw_idx(63, lane)] = E2;
#pragma unroll 1
    for (int ii = 63; ii >= 1; --ii) {
      float th = th_lds[c * 64 + ii];
      float Em1 = dpp_shr1(E2, NEG_C);
      E2 = fast_la(E2, Em1 + th);
      if (lane < 32) wb[sw_idx(ii - 1, lane)] = E2;
    }
    // Forward F over chunk; overwrite each consumed B row with comb = F + B.
    float F2;
    if (c == 0) F2 = (lane == 0) ? 0.0f : NEG_C;
    else        F2 = (lane < 32) ? chkF[(c - 1) * 32 + lane] : NEG_C;
    float th = th_lds[c * 64];
#pragma unroll 2
    for (int ii = 0; ii < 64; ++ii) {
      float th_nx = th_lds[c * 64 + ((ii + 1 < 64) ? ii + 1 : ii)];
      float bbv = wb[sw_idx(ii, (31 - lane) & 31)];   // B[i+1][31-j]
      float comb = F2 + bbv;                          // F[i][j] + B[i+1][k-1-j]
      if (lane < 32) wb[sw_idx(ii, lane)] = comb;     // overwrite consumed row
      float Fm1 = dpp_shr1(F2, NEG_C);
      F2 = fast_la(F2, Fm1 + th);
      th = th_nx;
    }
    __threadfence_block();   // wave-local DS ordering (reads below see writes)
    // Per-lane marginal: lane l owns i = c*64 + l; reduce its comb row in regs.
    float cb[32];
#pragma unroll
    for (int jj = 0; jj < 32; ++jj) cb[jj] = wb[sw_idx(lane, jj)];
    float amax = cb[0];
#pragma unroll
    for (int jj = 1; jj < 32; ++jj) amax = fmaxf(amax, cb[jj]);
    float ss = 0.0f;
#pragma unroll
    for (int jj = 0; jj < 32; ++jj) ss += __expf(cb[jj] - amax);
    float thi = th_lds[c * 64 + lane];
    float m = __expf((thi + (__logf(ss) + amax)) - logZ);
    out[OUT_HALF + bi * (N_C * 2) + (c * 64 + lane) * 2 + ens] = m;
  }
  __syncthreads();

  // ---- Phase 3: sequential conditional-Poisson walk (wave 0), bit-exact ----
  if (w == 0) {
    int r = K_C;
    for (int c = 0; c < 64; ++c) {
      const int i = c * 64 + lane;
      const int oidx = bi * (N_C * 2) + i * 2 + ens;
      float mval = out[OUT_HALF + oidx];
      unsigned mymask = __float_as_uint(out[oidx]);   // stashed mask
      unsigned incl = 0u;
#pragma unroll 8
      for (int ii = 0; ii < 64; ++ii) {
        unsigned mm = (unsigned)__builtin_amdgcn_readlane((int)mymask, ii);
        unsigned bit = (mm >> ((unsigned)(r - 1) & 31u)) & 1u;
        bit = (r > 0) ? bit : 0u;
        if (lane == ii) incl = bit;
        r -= (int)bit;
      }
      float sval = incl ? ((1.0f - mval) + mval) : 0.0f;   // (s-m)+m
      out[oidx] = sval;
    }
  }
}

extern "C" void kernel_launch(void* const* d_in, const int* in_sizes, int n_in,
                              void* d_out, int out_size, void* d_ws, size_t ws_size,
                              hipStream_t stream) {
  (void)in_sizes; (void)n_in; (void)d_ws; (void)ws_size; (void)out_size;
  const float* scores = (const float*)d_in[0];
  float* out = (float*)d_out;
  EdgeSIMPLEBatched_39298950758997_kernel<<<dim3(BE_C), dim3(256), 0, stream>>>(scores, out);
}

// Round 5
// 1215.545 us; speedup vs baseline: 3.8302x; 1.0157x over previous
//
#include <hip/hip_runtime.h>
#include <stdint.h>

// Keep mul+add sequences UNFUSED so we bit-match XLA:CPU's unfused MulAdd ops.
#pragma clang fp contract(off)

#define BE_C     256
#define N_C      4096
#define K_C      32
#define NEG_C    (-1e30f)
#define OUT_HALF 1048576

// ---------------- XLA:CPU exp, trimmed for x <= 0 ----------------
// Identities used (bit-exact for all inputs that occur here):
//   fminf(x, exp_hi) == x for x <= 0;  fmaxf(y*s, x) == y*s since y*s >= 0 >= x.
__device__ __forceinline__ float xla_exp_neg(float x) {
  const float exp_lo = -88.3762626647949f;
  const float log2ef = 1.44269504088896341f;
  const float c1 = 0.693359375f;
  const float c2 = -2.12194440e-4f;
  const float p0 = 1.9875691500E-4f;
  const float p1 = 1.3981999507E-3f;
  const float p2 = 8.3334519073E-3f;
  const float p3 = 4.1665795894E-2f;
  const float p4 = 1.6666665459E-1f;
  const float p5 = 5.0000001201E-1f;
  float xc = fmaxf(x, exp_lo);
  float fx = floorf(xc * log2ef + 0.5f);
  float tmp = c1 * fx;
  float z = c2 * fx;
  float xx = xc - tmp;
  xx = xx - z;
  z = xx * xx;
  float y = xx * p0 + p1;
  y = y * xx + p2;
  y = y * xx + p3;
  y = y * xx + p4;
  y = y * xx + p5;
  y = y * z + xx;
  y = y + 1.0f;
  int ei = (int)fx;
  float s = __int_as_float((ei + 127) << 23);
  return y * s;
}

// ---------------- XLA:CPU log, trimmed for x in [1,2] ----------------
// fmaxf(x, min_norm) == x for x >= 1 (bit-identity).
__device__ __forceinline__ float xla_log_12(float xin) {
  const float sqrthf = 0.707106781186547524f;
  const float p0 = 7.0376836292E-2f;
  const float p1 = -1.1514610310E-1f;
  const float p2 = 1.1676998740E-1f;
  const float p3 = -1.2420140846E-1f;
  const float p4 = 1.4249322787E-1f;
  const float p5 = -1.6668057665E-1f;
  const float p6 = 2.0000714765E-1f;
  const float p7 = -2.4999993993E-1f;
  const float p8 = 3.3333331174E-1f;
  const float q1 = -2.12194440e-4f;
  const float q2 = 0.693359375f;
  float x = xin;
  unsigned ub = __float_as_uint(x);
  int emm0 = (int)(ub >> 23) - 0x7f;
  float e = 1.0f + (float)emm0;
  x = __uint_as_float((ub & 0x007fffffu) | 0x3f000000u);
  bool mlt = x < sqrthf;
  float tmp = mlt ? x : 0.0f;
  x = x - 1.0f;
  e = e - (mlt ? 1.0f : 0.0f);
  x = x + tmp;
  float x2 = x * x;
  float x3 = x2 * x;
  float y  = x * p0 + p1;
  float y1 = x * p3 + p4;
  float y2 = x * p6 + p7;
  y  = y * x + p2;
  y1 = y1 * x + p5;
  y2 = y2 * x + p8;
  y = y * x3 + y1;
  y = y * x3 + y2;
  y = y * x3;
  y1 = q1 * e;
  float t2 = 0.5f * x2;
  y = y + y1;
  x = x - t2;
  y2 = q2 * e;
  x = x + y;
  x = x + y2;
  return x;
}

// XLA elemental log1p for e in [0,1]: |e|<1e-4 ? e*(1-e/2) : log(e+1)
__device__ __forceinline__ float xla_log1p_01(float x) {
  float fsmall = ((-0.5f * x) + 1.0f) * x;
  float flarge = xla_log_12(x + 1.0f);
  return (fabsf(x) < 1e-4f) ? fsmall : flarge;
}

// jnp.logaddexp, exact bits, inputs finite: max + log1p(exp(-|a-b|))
__device__ __forceinline__ float xla_logaddexp(float a, float b) {
  float mx = fmaxf(a, b);
  float d = a - b;
  float e = xla_exp_neg(-fabsf(d));
  return mx + xla_log1p_01(e);
}

// Fast path (2e-2 tolerance consumers only: marginals).
__device__ __forceinline__ float fast_la(float a, float b) {
  float mx = fmaxf(a, b);
  float d = a - b;
  float e = __expf(-fabsf(d));
  return mx + __logf(1.0f + e);
}

// Full-wave shift-right-by-1 via DPP (wave_shr:1 = 0x138). Lane 0 <- fill.
__device__ __forceinline__ float dpp_shr1(float x, float fill) {
  int r = __builtin_amdgcn_update_dpp(__float_as_int(fill), __float_as_int(x),
                                      0x138, 0xF, 0xF, false);
  return __int_as_float(r);
}

__device__ __forceinline__ float readlane_f(float v, int l) {
  return __int_as_float(__builtin_amdgcn_readlane(__float_as_int(v), l));
}

// ---------------- Threefry-2x32, key = (0, 42), 20 rounds ----------------
__device__ __forceinline__ unsigned rotl_(unsigned v, int r) {
  return (v << r) | (v >> (32 - r));
}

__device__ __forceinline__ void threefry_0_42(unsigned c0, unsigned c1,
                                              unsigned* o0, unsigned* o1) {
  const unsigned ks0 = 0u, ks1 = 42u, ks2 = 0x1BD11BDAu ^ 0u ^ 42u;
  unsigned x0 = c0 + ks0, x1 = c1 + ks1;
  x0 += x1; x1 = rotl_(x1, 13); x1 ^= x0;
  x0 += x1; x1 = rotl_(x1, 15); x1 ^= x0;
  x0 += x1; x1 = rotl_(x1, 26); x1 ^= x0;
  x0 += x1; x1 = rotl_(x1, 6);  x1 ^= x0;
  x0 += ks1; x1 += ks2 + 1u;
  x0 += x1; x1 = rotl_(x1, 17); x1 ^= x0;
  x0 += x1; x1 = rotl_(x1, 29); x1 ^= x0;
  x0 += x1; x1 = rotl_(x1, 16); x1 ^= x0;
  x0 += x1; x1 = rotl_(x1, 24); x1 ^= x0;
  x0 += ks2; x1 += ks0 + 2u;
  x0 += x1; x1 = rotl_(x1, 13); x1 ^= x0;
  x0 += x1; x1 = rotl_(x1, 15); x1 ^= x0;
  x0 += x1; x1 = rotl_(x1, 26); x1 ^= x0;
  x0 += x1; x1 = rotl_(x1, 6);  x1 ^= x0;
  x0 += ks0; x1 += ks1 + 3u;
  x0 += x1; x1 = rotl_(x1, 17); x1 ^= x0;
  x0 += x1; x1 = rotl_(x1, 29); x1 ^= x0;
  x0 += x1; x1 = rotl_(x1, 16); x1 ^= x0;
  x0 += x1; x1 = rotl_(x1, 24); x1 ^= x0;
  x0 += ks1; x1 += ks2 + 4u;
  x0 += x1; x1 = rotl_(x1, 13); x1 ^= x0;
  x0 += x1; x1 = rotl_(x1, 15); x1 ^= x0;
  x0 += x1; x1 = rotl_(x1, 26); x1 ^= x0;
  x0 += x1; x1 = rotl_(x1, 6);  x1 ^= x0;
  x0 += ks2; x1 += ks0 + 5u;
  *o0 = x0; *o1 = x1;
}

__device__ __forceinline__ float u01_from_idx(unsigned idx) {
  unsigned b0, b1;
  threefry_0_42(0u, idx, &b0, &b1);     // jax_threefry_partitionable
  unsigned bits = b0 ^ b1;
  unsigned fb = (bits >> 9) | 0x3f800000u;
  return __uint_as_float(fb) - 1.0f;
}

// XOR-swizzled 64x32 tile: conflict-free col-writes AND row-reads.
__device__ __forceinline__ int sw_idx(int row, int col) {
  return row * 32 + ((col + row) & 31);
}

// ---------------- main kernel: one block (4 waves) per row b = bi*2 + ens ----------------
__global__ __launch_bounds__(256)
void EdgeSIMPLEBatched_39298950758997_kernel(const float* __restrict__ scores,
                                             float* __restrict__ out) {
  __shared__ float th_lds[N_C];          // 16384 B
  __shared__ float chkB[64 * 32];        // 8192 B: chkB[c] = exact B-row 64(c+1)
  __shared__ float chkF[63 * 32];        // 8064 B: chkF[c-1] = F-state at chunk c
  __shared__ float logZ_s;
  __shared__ union OvT {
    float u[N_C];                        // 16384 B: uniforms (phase 0/1 only)
    float wbuf[4][64 * 32];              // 32768 B: per-wave tile (phase 2 only)
  } ov;

  const int t = threadIdx.x;
  const int w = t >> 6;
  const int lane = t & 63;
  const int b = blockIdx.x;
  const int bi = b >> 1, ens = b & 1;
  const float* srow = scores + bi * (N_C * 2) + ens;
  const int obase = bi * (N_C * 2) + ens;

  // ---- Phase 0: stage theta + uniforms ----
  for (int idx = t; idx < N_C; idx += 256) {
    th_lds[idx] = srow[idx * 2];
    ov.u[idx] = u01_from_idx((unsigned)(idx * BE_C + b));
  }
  __syncthreads();

  // ---- Phase 1 ----
  if (w == 0) {
    // EXACT backward B chain. Zero memory ops on the chain: th/u batch-preloaded
    // into VGPRs (wave-uniform per i -> readlane), mask bits accumulated
    // transposed per-lane, one global_store per 32-iter group.
    float E = (lane == 0) ? 0.0f : NEG_C;
    if (lane < 32) chkB[63 * 32 + lane] = E;     // B-row 4096 = init
    const int l31 = lane & 31;
    float thb = th_lds[N_C - 1 - l31];           // batch 0: i = 4095 - l
    float ub  = ov.u[N_C - 1 - l31];
    unsigned Wbits = 0u;
#pragma unroll 1
    for (int g = 0; g < 128; ++g) {
      const int nb = (g + 1 < 128) ? g + 1 : g;  // prefetch next batch (dbuf)
      float thb_n = th_lds[N_C - 1 - nb * 32 - l31];
      float ub_n  = ov.u[N_C - 1 - nb * 32 - l31];
#pragma unroll 4
      for (int l = 0; l < 32; ++l) {
        float th = readlane_f(thb, l);           // wave-uniform scalar, off-chain
        float u  = readlane_f(ub, l);
        float Em1 = dpp_shr1(E, NEG_C);          // B[i+1][j-1]
        float sh = Em1 + th;
        float Enew = xla_logaddexp(E, sh);       // EXACT chain (trimmed identities)
        float logq = (th + Em1) - Enew;          // exact, ref op order
        float q = xla_exp_neg(fminf(logq, 0.0f));// off-chain
        unsigned pb = (u < q) ? 1u : 0u;
        Wbits |= pb << l;                        // bit l <-> i = 4095 - 32g - l
        E = Enew;
      }
      // Stash transposed mask word: lane j (1..32) -> slot (127-g)*32 + j-1.
      if (lane >= 1 && lane <= 32)
        out[obase + ((127 - g) * 32 + lane - 1) * 2] = __uint_as_float(Wbits);
      Wbits = 0u;
      // Checkpoint: after odd g, E = B-row i0 = 32*(127-g) = 64c, c=(127-g)/2.
      if ((g & 1) == 1 && g < 127 && lane < 32)
        chkB[(((127 - g) >> 1) - 1) * 32 + lane] = E;
      thb = thb_n; ub = ub_n;
    }
    if (lane == 32) logZ_s = E;                  // B[0][k]
  } else if (w == 1) {
    // Fast forward F scan, checkpoint every 64 rows.
    float F = (lane == 0) ? 0.0f : NEG_C;
    float th = th_lds[0];
#pragma unroll 2
    for (int i = 0; i < N_C; ++i) {
      float th_nx = th_lds[(i + 1 < N_C) ? i + 1 : i];
      if ((i & 63) == 0 && i > 0 && lane < 32) chkF[((i >> 6) - 1) * 32 + lane] = F;
      float Fm1 = dpp_shr1(F, NEG_C);
      F = fast_la(F, Fm1 + th);
      th = th_nx;
    }
  }
  __syncthreads();

  // ---- Phase 2: marginals, 4-wave chunk-parallel, per-lane register logsumexp ----
  const float logZ = logZ_s;
  float* wb = ov.wbuf[w];
  for (int c = w; c < 64; c += 4) {
    // Regen B rows c*64+1 .. c*64+64 into wb (row ii holds B[c*64+ii+1]).
    float E2 = chkB[c * 32 + (lane & 31)];
    if (lane < 32) wb[sw_idx(63, lane)] = E2;
#pragma unroll 1
    for (int ii = 63; ii >= 1; --ii) {
      float th = th_lds[c * 64 + ii];
      float Em1 = dpp_shr1(E2, NEG_C);
      E2 = fast_la(E2, Em1 + th);
      if (lane < 32) wb[sw_idx(ii - 1, lane)] = E2;
    }
    // Forward F over chunk; overwrite each consumed B row with comb = F + B.
    float F2;
    if (c == 0) F2 = (lane == 0) ? 0.0f : NEG_C;
    else        F2 = (lane < 32) ? chkF[(c - 1) * 32 + lane] : NEG_C;
    float th = th_lds[c * 64];
#pragma unroll 2
    for (int ii = 0; ii < 64; ++ii) {
      float th_nx = th_lds[c * 64 + ((ii + 1 < 64) ? ii + 1 : ii)];
      float bbv = wb[sw_idx(ii, (31 - lane) & 31)];   // B[i+1][31-j]
      float comb = F2 + bbv;                          // F[i][j] + B[i+1][k-1-j]
      if (lane < 32) wb[sw_idx(ii, lane)] = comb;     // overwrite consumed row
      float Fm1 = dpp_shr1(F2, NEG_C);
      F2 = fast_la(F2, Fm1 + th);
      th = th_nx;
    }
    __threadfence_block();   // wave-local DS ordering (reads below see writes)
    // Per-lane marginal: lane l owns i = c*64 + l; reduce its comb row in regs.
    float cb[32];
#pragma unroll
    for (int jj = 0; jj < 32; ++jj) cb[jj] = wb[sw_idx(lane, jj)];
    float amax = cb[0];
#pragma unroll
    for (int jj = 1; jj < 32; ++jj) amax = fmaxf(amax, cb[jj]);
    float ss = 0.0f;
#pragma unroll
    for (int jj = 0; jj < 32; ++jj) ss += __expf(cb[jj] - amax);
    float thi = th_lds[c * 64 + lane];
    float m = __expf((thi + (__logf(ss) + amax)) - logZ);
    out[OUT_HALF + obase + (c * 64 + lane) * 2] = m;
  }
  __syncthreads();

  // ---- Phase 3: sequential conditional-Poisson walk (wave 0), bit-exact ----
  if (w == 0) {
    int r = K_C;
    const int l31 = lane & 31;
    // Wv for group g lives at slots (127-g)*32 + (j-1); lanes 0,33..63 hold 0
    // so readlane(Wv, 0) == 0 implements the (r > 0) guard.
    unsigned Wv = 0u;
    if (lane >= 1 && lane <= 32)
      Wv = __float_as_uint(out[obase + (lane - 1) * 2]);     // group 127
#pragma unroll 1
    for (int g = 127; g >= 0; --g) {
      unsigned Wn = 0u;
      if (g > 0 && lane >= 1 && lane <= 32)
        Wn = __float_as_uint(out[obase + ((128 - g) * 32 + lane - 1) * 2]);
      const int i_l = N_C - 1 - 32 * g - l31;      // this group's element for lane l
      float mval = out[OUT_HALF + obase + i_l * 2];
      unsigned inclW = 0u;
#pragma unroll 8
      for (int l = 31; l >= 0; --l) {              // i ascending within group
        unsigned mm = (unsigned)__builtin_amdgcn_readlane((int)Wv, r);
        unsigned bit = (mm >> l) & 1u;
        inclW |= bit << l;
        r -= (int)bit;
      }
      if (lane < 32) {
        unsigned incl = (inclW >> l31) & 1u;
        float sval = incl ? ((1.0f - mval) + mval) : 0.0f;   // (s-m)+m
        out[obase + i_l * 2] = sval;               // overwrites this group's own W
      }
      Wv = Wn;
    }
  }
}

extern "C" void kernel_launch(void* const* d_in, const int* in_sizes, int n_in,
                              void* d_out, int out_size, void* d_ws, size_t ws_size,
                              hipStream_t stream) {
  (void)in_sizes; (void)n_in; (void)d_ws; (void)ws_size; (void)out_size;
  const float* scores = (const float*)d_in[0];
  float* out = (float*)d_out;
  EdgeSIMPLEBatched_39298950758997_kernel<<<dim3(BE_C), dim3(256), 0, stream>>>(scores, out);
}

// Round 6
// 1018.539 us; speedup vs baseline: 4.5710x; 1.1934x over previous
//
#include <hip/hip_runtime.h>
#include <stdint.h>

// Keep mul+add sequences UNFUSED so we bit-match XLA:CPU's unfused MulAdd ops.
#pragma clang fp contract(off)

#define BE_C     256
#define N_C      4096
#define K_C      32
#define NEG_C    (-1e30f)
#define OUT_HALF 1048576

// ---------------- XLA:CPU exp, trimmed for x <= 0 (bit-exact identities) ----------------
__device__ __forceinline__ float xla_exp_neg(float x) {
  const float exp_lo = -88.3762626647949f;
  const float log2ef = 1.44269504088896341f;
  const float c1 = 0.693359375f;
  const float c2 = -2.12194440e-4f;
  const float p0 = 1.9875691500E-4f;
  const float p1 = 1.3981999507E-3f;
  const float p2 = 8.3334519073E-3f;
  const float p3 = 4.1665795894E-2f;
  const float p4 = 1.6666665459E-1f;
  const float p5 = 5.0000001201E-1f;
  float xc = fmaxf(x, exp_lo);
  float fx = floorf(xc * log2ef + 0.5f);
  float tmp = c1 * fx;
  float z = c2 * fx;
  float xx = xc - tmp;
  xx = xx - z;
  z = xx * xx;
  float y = xx * p0 + p1;
  y = y * xx + p2;
  y = y * xx + p3;
  y = y * xx + p4;
  y = y * xx + p5;
  y = y * z + xx;
  y = y + 1.0f;
  int ei = (int)fx;
  float s = __int_as_float((ei + 127) << 23);
  return y * s;
}

// ---------------- XLA:CPU log, trimmed for x in [1,2] ----------------
__device__ __forceinline__ float xla_log_12(float xin) {
  const float sqrthf = 0.707106781186547524f;
  const float p0 = 7.0376836292E-2f;
  const float p1 = -1.1514610310E-1f;
  const float p2 = 1.1676998740E-1f;
  const float p3 = -1.2420140846E-1f;
  const float p4 = 1.4249322787E-1f;
  const float p5 = -1.6668057665E-1f;
  const float p6 = 2.0000714765E-1f;
  const float p7 = -2.4999993993E-1f;
  const float p8 = 3.3333331174E-1f;
  const float q1 = -2.12194440e-4f;
  const float q2 = 0.693359375f;
  float x = xin;
  unsigned ub = __float_as_uint(x);
  int emm0 = (int)(ub >> 23) - 0x7f;
  float e = 1.0f + (float)emm0;
  x = __uint_as_float((ub & 0x007fffffu) | 0x3f000000u);
  bool mlt = x < sqrthf;
  float tmp = mlt ? x : 0.0f;
  x = x - 1.0f;
  e = e - (mlt ? 1.0f : 0.0f);
  x = x + tmp;
  float x2 = x * x;
  float x3 = x2 * x;
  float y  = x * p0 + p1;
  float y1 = x * p3 + p4;
  float y2 = x * p6 + p7;
  y  = y * x + p2;
  y1 = y1 * x + p5;
  y2 = y2 * x + p8;
  y = y * x3 + y1;
  y = y * x3 + y2;
  y = y * x3;
  y1 = q1 * e;
  float t2 = 0.5f * x2;
  y = y + y1;
  x = x - t2;
  y2 = q2 * e;
  x = x + y;
  x = x + y2;
  return x;
}

// XLA elemental log1p for e in [0,1]
__device__ __forceinline__ float xla_log1p_01(float x) {
  float fsmall = ((-0.5f * x) + 1.0f) * x;
  float flarge = xla_log_12(x + 1.0f);
  return (fabsf(x) < 1e-4f) ? fsmall : flarge;
}

// jnp.logaddexp, exact bits
__device__ __forceinline__ float xla_logaddexp(float a, float b) {
  float mx = fmaxf(a, b);
  float d = a - b;
  float e = xla_exp_neg(-fabsf(d));
  return mx + xla_log1p_01(e);
}

// Fast path (2e-2 tolerance consumers only: marginals).
__device__ __forceinline__ float fast_la(float a, float b) {
  float mx = fmaxf(a, b);
  float d = a - b;
  float e = __expf(-fabsf(d));
  return mx + __logf(1.0f + e);
}

// Full-wave shift-right-by-1 via DPP (wave_shr:1 = 0x138). Lane 0 <- fill.
__device__ __forceinline__ float dpp_shr1(float x, float fill) {
  int r = __builtin_amdgcn_update_dpp(__float_as_int(fill), __float_as_int(x),
                                      0x138, 0xF, 0xF, false);
  return __int_as_float(r);
}

__device__ __forceinline__ float readlane_f(float v, int l) {
  return __int_as_float(__builtin_amdgcn_readlane(__float_as_int(v), l));
}

// ---------------- Threefry-2x32, key = (0, 42), 20 rounds ----------------
__device__ __forceinline__ unsigned rotl_(unsigned v, int r) {
  return (v << r) | (v >> (32 - r));
}

__device__ __forceinline__ void threefry_0_42(unsigned c0, unsigned c1,
                                              unsigned* o0, unsigned* o1) {
  const unsigned ks0 = 0u, ks1 = 42u, ks2 = 0x1BD11BDAu ^ 0u ^ 42u;
  unsigned x0 = c0 + ks0, x1 = c1 + ks1;
  x0 += x1; x1 = rotl_(x1, 13); x1 ^= x0;
  x0 += x1; x1 = rotl_(x1, 15); x1 ^= x0;
  x0 += x1; x1 = rotl_(x1, 26); x1 ^= x0;
  x0 += x1; x1 = rotl_(x1, 6);  x1 ^= x0;
  x0 += ks1; x1 += ks2 + 1u;
  x0 += x1; x1 = rotl_(x1, 17); x1 ^= x0;
  x0 += x1; x1 = rotl_(x1, 29); x1 ^= x0;
  x0 += x1; x1 = rotl_(x1, 16); x1 ^= x0;
  x0 += x1; x1 = rotl_(x1, 24); x1 ^= x0;
  x0 += ks2; x1 += ks0 + 2u;
  x0 += x1; x1 = rotl_(x1, 13); x1 ^= x0;
  x0 += x1; x1 = rotl_(x1, 15); x1 ^= x0;
  x0 += x1; x1 = rotl_(x1, 26); x1 ^= x0;
  x0 += x1; x1 = rotl_(x1, 6);  x1 ^= x0;
  x0 += ks0; x1 += ks1 + 3u;
  x0 += x1; x1 = rotl_(x1, 17); x1 ^= x0;
  x0 += x1; x1 = rotl_(x1, 29); x1 ^= x0;
  x0 += x1; x1 = rotl_(x1, 16); x1 ^= x0;
  x0 += x1; x1 = rotl_(x1, 24); x1 ^= x0;
  x0 += ks1; x1 += ks2 + 4u;
  x0 += x1; x1 = rotl_(x1, 13); x1 ^= x0;
  x0 += x1; x1 = rotl_(x1, 15); x1 ^= x0;
  x0 += x1; x1 = rotl_(x1, 26); x1 ^= x0;
  x0 += x1; x1 = rotl_(x1, 6);  x1 ^= x0;
  x0 += ks2; x1 += ks0 + 5u;
  *o0 = x0; *o1 = x1;
}

__device__ __forceinline__ float u01_from_idx(unsigned idx) {
  unsigned b0, b1;
  threefry_0_42(0u, idx, &b0, &b1);     // jax_threefry_partitionable
  unsigned bits = b0 ^ b1;
  unsigned fb = (bits >> 9) | 0x3f800000u;
  return __uint_as_float(fb) - 1.0f;
}

// XOR-swizzled 64x32 tile: conflict-free col-writes AND row-reads.
__device__ __forceinline__ int sw_idx(int row, int col) {
  return row * 32 + ((col + row) & 31);
}

// ---------------- main kernel: one block (4 waves) per row b = bi*2 + ens ----------------
__global__ __launch_bounds__(256)
void EdgeSIMPLEBatched_39298950758997_kernel(const float* __restrict__ scores,
                                             float* __restrict__ out) {
  __shared__ float th_lds[N_C];          // 16384 B
  __shared__ float chkB[64 * 32];        // 8192 B: chkB[c] = exact B-row 64(c+1)
  __shared__ float chkF[63 * 32];        // 8064 B: chkF[c-1] = F-state at chunk c
  __shared__ float wbuf[4][64 * 32];     // 32768 B: per-wave tile
  __shared__ float logZ_s;
  __shared__ int   bReady;               // lowest chkB index published (desc)
  __shared__ int   fReady;               // highest chunk whose chkF is ready (asc)
  __shared__ int   claimIdx;             // phase-2 chunk claim counter

  const int t = threadIdx.x;
  const int w = t >> 6;
  const int lane = t & 63;
  const int b = blockIdx.x;
  const int bi = b >> 1, ens = b & 1;
  const float* srow = scores + bi * (N_C * 2) + ens;
  const int obase = bi * (N_C * 2) + ens;
  const int l31 = lane & 31;

  // ---- Phase 0: stage theta; init flags ----
  for (int idx = t; idx < N_C; idx += 256) th_lds[idx] = srow[idx * 2];
  if (t == 0) { bReady = 64; fReady = 0; claimIdx = 0; }
  __syncthreads();

  // ---- Phase 1 (roles) + overlapped phase 2 (worker pool) ----
  if (w == 0) {
    // PRODUCER: exact backward B chain + masks + chkB watermarks.
    float E = (lane == 0) ? 0.0f : NEG_C;
    if (lane < 32) chkB[63 * 32 + lane] = E;     // B-row 4096 = init
    __threadfence_block();
    if (lane == 0) *(volatile int*)&bReady = 63;
    float thb = th_lds[N_C - 1 - l31];
    float ub  = u01_from_idx((unsigned)((N_C - 1 - l31) * BE_C + b));
    unsigned Wbits = 0u;
#pragma unroll 1
    for (int g = 0; g < 128; ++g) {
      const int nb = (g + 1 < 128) ? g + 1 : g;  // prefetch next group (dbuf)
      float thb_n = th_lds[N_C - 1 - nb * 32 - l31];
      float ub_n  = u01_from_idx((unsigned)((N_C - 1 - nb * 32 - l31) * BE_C + b));
#pragma unroll 4
      for (int l = 0; l < 32; ++l) {
        float th = readlane_f(thb, l);           // wave-uniform, off-chain
        float u  = readlane_f(ub, l);
        float Em1 = dpp_shr1(E, NEG_C);          // B[i+1][j-1]
        float sh = Em1 + th;
        float Enew = xla_logaddexp(E, sh);       // EXACT chain
        float logq = (th + Em1) - Enew;          // exact, ref op order
        float q = xla_exp_neg(fminf(logq, 0.0f));// off-chain
        unsigned pb = (u < q) ? 1u : 0u;
        Wbits |= pb << l;                        // bit l <-> i = 4095 - 32g - l
        E = Enew;
      }
      if (lane >= 1 && lane <= 32)               // transposed mask stash
        out[obase + ((127 - g) * 32 + lane - 1) * 2] = __uint_as_float(Wbits);
      Wbits = 0u;
      if ((g & 1) == 1 && g < 127) {             // checkpoint + watermark
        const int c = ((127 - g) >> 1) - 1;
        if (lane < 32) chkB[c * 32 + lane] = E;
        __threadfence_block();
        if (lane == 0) *(volatile int*)&bReady = c;
      }
      thb = thb_n; ub = ub_n;
    }
    if (lane == 32) logZ_s = E;                  // B[0][k]
    __threadfence_block();
    if (lane == 0) *(volatile int*)&bReady = 0;  // (redundant; ensures 0)
  } else if (w == 1) {
    // Fast forward F scan, checkpoint + watermark every 64 rows.
    float F = (lane == 0) ? 0.0f : NEG_C;
    float th = th_lds[0];
#pragma unroll 2
    for (int i = 0; i < N_C; ++i) {
      float th_nx = th_lds[(i + 1 < N_C) ? i + 1 : i];
      if ((i & 63) == 0 && i > 0) {
        if (lane < 32) chkF[((i >> 6) - 1) * 32 + lane] = F;
        __threadfence_block();
        if (lane == 0) *(volatile int*)&fReady = (i >> 6);
      }
      float Fm1 = dpp_shr1(F, NEG_C);
      F = fast_la(F, Fm1 + th);
      th = th_nx;
    }
  }

  // ---- Worker pool: marginal chunks, claimed desc-c, gated on watermarks ----
  {
    float* wb = wbuf[w];
    for (;;) {
      int idxv = 0;
      if (lane == 0) idxv = atomicAdd(&claimIdx, 1);
      idxv = __shfl(idxv, 0);
      if (idxv >= 64) break;
      const int c = 63 - idxv;
      while (*(volatile int*)&bReady > c) __builtin_amdgcn_s_sleep(2);
      while (*(volatile int*)&fReady < c) __builtin_amdgcn_s_sleep(2);
      // Regen B rows c*64+1 .. c*64+64 into wb (row ii holds B[c*64+ii+1]).
      float E2 = chkB[c * 32 + l31];
      if (lane < 32) wb[sw_idx(63, lane)] = E2;
#pragma unroll 1
      for (int ii = 63; ii >= 1; --ii) {
        float th = th_lds[c * 64 + ii];
        float Em1 = dpp_shr1(E2, NEG_C);
        E2 = fast_la(E2, Em1 + th);
        if (lane < 32) wb[sw_idx(ii - 1, lane)] = E2;
      }
      // Forward F over chunk; overwrite each consumed B row with comb = F + B.
      float F2;
      if (c == 0) F2 = (lane == 0) ? 0.0f : NEG_C;
      else        F2 = (lane < 32) ? chkF[(c - 1) * 32 + lane] : NEG_C;
      float th = th_lds[c * 64];
#pragma unroll 2
      for (int ii = 0; ii < 64; ++ii) {
        float th_nx = th_lds[c * 64 + ((ii + 1 < 64) ? ii + 1 : ii)];
        float bbv = wb[sw_idx(ii, (31 - lane) & 31)];   // B[i+1][31-j]
        float comb = F2 + bbv;                          // F[i][j] + B[i+1][k-1-j]
        if (lane < 32) wb[sw_idx(ii, lane)] = comb;
        float Fm1 = dpp_shr1(F2, NEG_C);
        F2 = fast_la(F2, Fm1 + th);
        th = th_nx;
      }
      __threadfence_block();
      // Per-lane logsumexp of own comb row; store mraw (logZ applied later).
      float cb[32];
#pragma unroll
      for (int jj = 0; jj < 32; ++jj) cb[jj] = wb[sw_idx(lane, jj)];
      float amax = cb[0];
#pragma unroll
      for (int jj = 1; jj < 32; ++jj) amax = fmaxf(amax, cb[jj]);
      float ss = 0.0f;
#pragma unroll
      for (int jj = 0; jj < 32; ++jj) ss += __expf(cb[jj] - amax);
      float thi = th_lds[c * 64 + lane];
      float mraw = thi + (__logf(ss) + amax);
      out[OUT_HALF + obase + (c * 64 + lane) * 2] = mraw;
    }
  }
  __syncthreads();

  // ---- Finalize marginals: m = exp(mraw - logZ) ----
  {
    const float logZ = logZ_s;
    for (int idx = t; idx < N_C; idx += 256) {
      const int o = OUT_HALF + obase + idx * 2;
      out[o] = __expf(out[o] - logZ);
    }
  }
  __syncthreads();

  // ---- Phase 3: sequential conditional-Poisson walk (wave 0), bit-exact ----
  if (w == 0) {
    int r = K_C;
    unsigned Wv = 0u;
    if (lane >= 1 && lane <= 32)
      Wv = __float_as_uint(out[obase + (lane - 1) * 2]);     // group 127
#pragma unroll 1
    for (int g = 127; g >= 0; --g) {
      unsigned Wn = 0u;
      if (g > 0 && lane >= 1 && lane <= 32)
        Wn = __float_as_uint(out[obase + ((128 - g) * 32 + lane - 1) * 2]);
      const int i_l = N_C - 1 - 32 * g - l31;
      float mval = out[OUT_HALF + obase + i_l * 2];
      unsigned inclW = 0u;
#pragma unroll 8
      for (int l = 31; l >= 0; --l) {              // i ascending within group
        unsigned mm = (unsigned)__builtin_amdgcn_readlane((int)Wv, r);
        unsigned bit = (mm >> l) & 1u;
        inclW |= bit << l;
        r -= (int)bit;
      }
      if (lane < 32) {
        unsigned incl = (inclW >> l31) & 1u;
        float sval = incl ? ((1.0f - mval) + mval) : 0.0f;   // (s-m)+m
        out[obase + i_l * 2] = sval;
      }
      Wv = Wn;
    }
  }
}

extern "C" void kernel_launch(void* const* d_in, const int* in_sizes, int n_in,
                              void* d_out, int out_size, void* d_ws, size_t ws_size,
                              hipStream_t stream) {
  (void)in_sizes; (void)n_in; (void)d_ws; (void)ws_size; (void)out_size;
  const float* scores = (const float*)d_in[0];
  float* out = (float*)d_out;
  EdgeSIMPLEBatched_39298950758997_kernel<<<dim3(BE_C), dim3(256), 0, stream>>>(scores, out);
}